// Round 1
// baseline (465.796 us; speedup 1.0000x reference)
//
#include <hip/hip_runtime.h>

// Problem constants (match reference)
constexpr int HSd = 192, WSd = 192, HRd = 192, WRd = 192;
constexpr int Cd  = 512;
constexpr int NS  = HSd * WSd;   // 36864 src pixels
constexpr int NR  = HRd * WRd;   // 36864 ref pixels
constexpr int CAP = 64;          // per-target dir2 list capacity (Poisson λ≈9)
constexpr float W_SRC = 1.0f / (float)NS;   // ws
constexpr float W_REF = 2.0f / (float)NR;   // wr
constexpr float TAUc   = 0.05f;
constexpr float ALPHAc = 0.8f;

// ---------------------------------------------------------------------------
// 0) init min/max (uint-encoded; response >= 0 so uint compare == float compare)
__global__ void init_minmax(unsigned int* minmax) {
    minmax[0] = 0x7F800000u;  // +inf
    minmax[1] = 0u;           // 0.0f
}

// ---------------------------------------------------------------------------
// 1) transpose ref [C][NR] -> ref_t [NR][C], 32x32 LDS tiles
__global__ __launch_bounds__(256)
void transpose_ref(const float* __restrict__ ref, float* __restrict__ ref_t) {
    __shared__ float tile[32][33];
    const int p0 = blockIdx.x * 32;   // pixel tile
    const int c0 = blockIdx.y * 32;   // channel tile
    const int tx = threadIdx.x;       // 0..31
    const int ty = threadIdx.y;       // 0..7
#pragma unroll
    for (int k = 0; k < 4; ++k) {
        const int c = c0 + ty + 8 * k;
        tile[ty + 8 * k][tx] = ref[(size_t)c * NR + (p0 + tx)];
    }
    __syncthreads();
#pragma unroll
    for (int k = 0; k < 4; ++k) {
        const int p = p0 + ty + 8 * k;
        ref_t[(size_t)p * Cd + (c0 + tx)] = tile[tx][ty + 8 * k];
    }
}

// ---------------------------------------------------------------------------
// 2) build dir2 (ref->src) contribution lists: index-only scatter
__global__ __launch_bounds__(256)
void build_list(const int* __restrict__ nnf_rs, int* __restrict__ cnt,
                int* __restrict__ list) {
    const int r = blockIdx.x * 256 + threadIdx.x;
    if (r >= NR) return;
    const int ry = r / WRd, rx = r % WRd;
    const int ty0 = nnf_rs[2 * r], tx0 = nnf_rs[2 * r + 1];
#pragma unroll
    for (int dy = -1; dy <= 1; ++dy) {
#pragma unroll
        for (int dx = -1; dx <= 1; ++dx) {
            const int ty = ty0 + dy, tx = tx0 + dx;
            const int gy = ry + dy,  gx = rx + dx;
            if (ty >= 0 && ty < HSd && tx >= 0 && tx < WSd &&
                gy >= 0 && gy < HRd && gx >= 0 && gx < WRd) {
                const int t = ty * WSd + tx;
                const int pos = atomicAdd(&cnt[t], 1);
                if (pos < CAP) list[t * CAP + pos] = gy * WRd + gx;
            }
        }
    }
}

// ---------------------------------------------------------------------------
// 3) response[t] = sum_c f_a[c][t]^2 ; global min/max via uint atomics
__global__ __launch_bounds__(256)
void response_kernel(const float* __restrict__ f_a, float* __restrict__ response,
                     unsigned int* __restrict__ minmax) {
    const int t4 = blockIdx.x * 256 + threadIdx.x;  // one float4 (4 pixels) per thread
    const float4* f4 = (const float4*)f_a;
    float4 acc = make_float4(0.f, 0.f, 0.f, 0.f);
    for (int c = 0; c < Cd; ++c) {
        const float4 v = f4[(size_t)c * (NS / 4) + t4];
        acc.x += v.x * v.x;
        acc.y += v.y * v.y;
        acc.z += v.z * v.z;
        acc.w += v.w * v.w;
    }
    ((float4*)response)[t4] = acc;
    const float mn = fminf(fminf(acc.x, acc.y), fminf(acc.z, acc.w));
    const float mx = fmaxf(fmaxf(acc.x, acc.y), fmaxf(acc.z, acc.w));
    atomicMin(&minmax[0], __float_as_uint(mn));
    atomicMax(&minmax[1], __float_as_uint(mx));
}

// ---------------------------------------------------------------------------
// 4) main vote gather: per target pixel, 9-tap dir1 gather + dir2 list gather
//    block = 256 threads = 2 groups x 128 lanes; each group owns one target,
//    lane covers 4 channels (float4) -> contiguous 2KB per contribution.
__global__ __launch_bounds__(256)
void gather_kernel(const float* __restrict__ ref_t, const int* __restrict__ nnf_sr,
                   const int* __restrict__ cnt, const int* __restrict__ list,
                   float* __restrict__ guide_t) {
    const int grp  = threadIdx.x >> 7;    // 0..1
    const int lane = threadIdx.x & 127;   // channel float4 index
    const int t = blockIdx.x * 2 + grp;
    const int ty = t / WSd, tx = t % WSd;

    const float4* rt4 = (const float4*)ref_t;
    float4 acc1 = make_float4(0.f, 0.f, 0.f, 0.f);  // dir1 (weight W_SRC)
    float4 acc2 = make_float4(0.f, 0.f, 0.f, 0.f);  // dir2 (weight W_REF)
    int n1 = 0;

#pragma unroll
    for (int dy = -1; dy <= 1; ++dy) {
#pragma unroll
        for (int dx = -1; dx <= 1; ++dx) {
            const int sy = ty - dy, sx = tx - dx;
            if (sy >= 0 && sy < HSd && sx >= 0 && sx < WSd) {
                const int s = sy * WSd + sx;
                const int gy = nnf_sr[2 * s] + dy;
                const int gx = nnf_sr[2 * s + 1] + dx;
                if (gy >= 0 && gy < HRd && gx >= 0 && gx < WRd) {
                    const int g = gy * WRd + gx;
                    const float4 v = rt4[(size_t)g * (Cd / 4) + lane];
                    acc1.x += v.x; acc1.y += v.y; acc1.z += v.z; acc1.w += v.w;
                    ++n1;
                }
            }
        }
    }

    const int n2 = min(cnt[t], CAP);
    for (int j = 0; j < n2; ++j) {
        const int g = list[t * CAP + j];
        const float4 v = rt4[(size_t)g * (Cd / 4) + lane];
        acc2.x += v.x; acc2.y += v.y; acc2.z += v.z; acc2.w += v.w;
    }

    const float wsum = (float)n1 * W_SRC + (float)n2 * W_REF;
    const float inv = (wsum == 0.f) ? 0.f : 1.f / wsum;  // wsum==0 -> guide 0 (ref: /1 of 0)
    float4 g4;
    g4.x = (acc1.x * W_SRC + acc2.x * W_REF) * inv;
    g4.y = (acc1.y * W_SRC + acc2.y * W_REF) * inv;
    g4.z = (acc1.z * W_SRC + acc2.z * W_REF) * inv;
    g4.w = (acc1.w * W_SRC + acc2.w * W_REF) * inv;
    ((float4*)guide_t)[(size_t)t * (Cd / 4) + lane] = g4;
}

// ---------------------------------------------------------------------------
// 5) fused transpose + blend: out[c][t] = f_a*w + guide*(1-w)
__global__ __launch_bounds__(256)
void fuse_kernel(const float* __restrict__ guide_t, const float* __restrict__ f_a,
                 const float* __restrict__ response, const unsigned int* __restrict__ minmax,
                 float* __restrict__ out) {
    __shared__ float tile[32][33];
    const int t0 = blockIdx.x * 32;
    const int c0 = blockIdx.y * 32;
    const int tx = threadIdx.x;  // 0..31
    const int ty = threadIdx.y;  // 0..7
    const float mn = __uint_as_float(minmax[0]);
    const float mx = __uint_as_float(minmax[1]);
    const float inv_range = 1.f / (mx - mn);
#pragma unroll
    for (int k = 0; k < 4; ++k) {
        const int t = t0 + ty + 8 * k;
        tile[ty + 8 * k][tx] = guide_t[(size_t)t * Cd + (c0 + tx)];
    }
    __syncthreads();
    const int t = t0 + tx;
    const float rn = (response[t] - mn) * inv_range;
    const float w = (rn > TAUc) ? ALPHAc : 0.f;
    const float omw = 1.f - w;
#pragma unroll
    for (int k = 0; k < 4; ++k) {
        const int c = c0 + ty + 8 * k;
        const float g = tile[tx][ty + 8 * k];
        const size_t idx = (size_t)c * NS + t;
        out[idx] = f_a[idx] * w + g * omw;
    }
}

// ---------------------------------------------------------------------------
extern "C" void kernel_launch(void* const* d_in, const int* in_sizes, int n_in,
                              void* d_out, int out_size, void* d_ws, size_t ws_size,
                              hipStream_t stream) {
    const float* ref    = (const float*)d_in[0];
    const float* f_a    = (const float*)d_in[1];
    const int*   nnf_sr = (const int*)d_in[2];
    const int*   nnf_rs = (const int*)d_in[3];
    float* out = (float*)d_out;

    char* ws = (char*)d_ws;
    size_t off = 0;
    float* ref_t = (float*)(ws + off);       off += (size_t)NR * Cd * sizeof(float);
    int*   list  = (int*)(ws + off);         off += (size_t)NS * CAP * sizeof(int);
    int*   cnt   = (int*)(ws + off);         off += (size_t)NS * sizeof(int);
    float* resp  = (float*)(ws + off);       off += (size_t)NS * sizeof(float);
    unsigned int* minmax = (unsigned int*)(ws + off); off += 16;

    float* guide_t;
    float* fuse_out;
    bool planB;
    if (ws_size >= off + (size_t)NS * Cd * sizeof(float)) {
        guide_t = (float*)(ws + off);  // plan A: guide staged in ws
        fuse_out = out;
        planB = false;
    } else {
        guide_t = out;        // plan B: stage guide (pixel-major) in d_out
        fuse_out = ref_t;     // final output into ref_t region (free after gather)
        planB = true;
    }

    hipMemsetAsync(cnt, 0, (size_t)NS * sizeof(int), stream);
    init_minmax<<<1, 1, 0, stream>>>(minmax);
    transpose_ref<<<dim3(NR / 32, Cd / 32), dim3(32, 8), 0, stream>>>(ref, ref_t);
    build_list<<<(NR + 255) / 256, 256, 0, stream>>>(nnf_rs, cnt, list);
    response_kernel<<<NS / 4 / 256, 256, 0, stream>>>(f_a, resp, minmax);
    gather_kernel<<<NS / 2, 256, 0, stream>>>(ref_t, nnf_sr, cnt, list, guide_t);
    fuse_kernel<<<dim3(NS / 32, Cd / 32), dim3(32, 8), 0, stream>>>(guide_t, f_a, resp, minmax, fuse_out);
    if (planB) {
        hipMemcpyAsync(out, fuse_out, (size_t)Cd * NS * sizeof(float),
                       hipMemcpyDeviceToDevice, stream);
    }
}

// Round 5
// 454.804 us; speedup vs baseline: 1.0242x; 1.0242x over previous
//
#include <hip/hip_runtime.h>

// Problem constants (match reference)
constexpr int HSd = 192, WSd = 192, HRd = 192, WRd = 192;
constexpr int Cd  = 512;
constexpr int NS  = HSd * WSd;   // 36864 src pixels
constexpr int NR  = HRd * WRd;   // 36864 ref pixels
constexpr int CAP = 64;          // per-target dir2 list capacity (Poisson λ≈8.7)
constexpr float W_SRC = 1.0f / (float)NS;   // ws
constexpr float W_REF = 2.0f / (float)NR;   // wr
constexpr float TAUc   = 0.05f;
constexpr float ALPHAc = 0.8f;

constexpr int TT  = 16;            // targets per block
constexpr int LPT = 16;            // lanes per target
constexpr int M4  = Cd / 4 / LPT;  // 8 float4 accumulators per lane
constexpr int LDS_STRIDE = 516;    // words; 516%32=4 -> 2-way conflicts (free), 16B aligned rows

// ---------------------------------------------------------------------------
// 0) init min/max (uint-encoded; response >= 0 so uint compare == float compare)
__global__ void init_minmax(unsigned int* minmax) {
    minmax[0] = 0x7F800000u;  // +inf
    minmax[1] = 0u;           // 0.0f
}

// ---------------------------------------------------------------------------
// 1) transpose ref [C][NR] -> ref_t [NR][C], 32x32 LDS tiles
__global__ __launch_bounds__(256)
void transpose_ref(const float* __restrict__ ref, float* __restrict__ ref_t) {
    __shared__ float tile[32][33];
    const int p0 = blockIdx.x * 32;   // pixel tile
    const int c0 = blockIdx.y * 32;   // channel tile
    const int tx = threadIdx.x;       // 0..31
    const int ty = threadIdx.y;       // 0..7
#pragma unroll
    for (int k = 0; k < 4; ++k) {
        const int c = c0 + ty + 8 * k;
        tile[ty + 8 * k][tx] = ref[(size_t)c * NR + (p0 + tx)];
    }
    __syncthreads();
#pragma unroll
    for (int k = 0; k < 4; ++k) {
        const int p = p0 + ty + 8 * k;
        ref_t[(size_t)p * Cd + (c0 + tx)] = tile[tx][ty + 8 * k];
    }
}

// ---------------------------------------------------------------------------
// 2) build dir2 (ref->src) contribution lists: index-only scatter
__global__ __launch_bounds__(256)
void build_list(const int* __restrict__ nnf_rs, int* __restrict__ cnt,
                int* __restrict__ list) {
    const int r = blockIdx.x * 256 + threadIdx.x;
    if (r >= NR) return;
    const int ry = r / WRd, rx = r % WRd;
    const int ty0 = nnf_rs[2 * r], tx0 = nnf_rs[2 * r + 1];
#pragma unroll
    for (int dy = -1; dy <= 1; ++dy) {
#pragma unroll
        for (int dx = -1; dx <= 1; ++dx) {
            const int ty = ty0 + dy, tx = tx0 + dx;
            const int gy = ry + dy,  gx = rx + dx;
            if (ty >= 0 && ty < HSd && tx >= 0 && tx < WSd &&
                gy >= 0 && gy < HRd && gx >= 0 && gx < WRd) {
                const int t = ty * WSd + tx;
                const int pos = atomicAdd(&cnt[t], 1);
                if (pos < CAP) list[t * CAP + pos] = gy * WRd + gx;
            }
        }
    }
}

// ---------------------------------------------------------------------------
// 3) response[t] = sum_c f_a[c][t]^2 ; global min/max via uint atomics
__global__ __launch_bounds__(256)
void response_kernel(const float* __restrict__ f_a, float* __restrict__ response,
                     unsigned int* __restrict__ minmax) {
    const int t4 = blockIdx.x * 256 + threadIdx.x;  // one float4 (4 pixels) per thread
    const float4* f4 = (const float4*)f_a;
    float4 acc = make_float4(0.f, 0.f, 0.f, 0.f);
    for (int c = 0; c < Cd; ++c) {
        const float4 v = f4[(size_t)c * (NS / 4) + t4];
        acc.x += v.x * v.x;
        acc.y += v.y * v.y;
        acc.z += v.z * v.z;
        acc.w += v.w * v.w;
    }
    ((float4*)response)[t4] = acc;
    const float mn = fminf(fminf(acc.x, acc.y), fminf(acc.z, acc.w));
    const float mx = fmaxf(fmaxf(acc.x, acc.y), fmaxf(acc.z, acc.w));
    atomicMin(&minmax[0], __float_as_uint(mn));
    atomicMax(&minmax[1], __float_as_uint(mx));
}

// ---------------------------------------------------------------------------
// 4) fused vote-gather + normalize + LDS transpose + blend + channel-major write.
//    Block = 256 threads = 16 targets x 16 lanes; lane covers 32 channels
//    (8 float4). Weighted accumulation folds W_SRC/W_REF at FMA time so a
//    single acc[8] suffices.
__global__ __launch_bounds__(256)
void gather_fused(const float* __restrict__ ref_t, const int* __restrict__ nnf_sr,
                  const int* __restrict__ cnt, const int* __restrict__ list,
                  const float* __restrict__ f_a, const float* __restrict__ resp,
                  const unsigned int* __restrict__ minmax,
                  float* __restrict__ out) {
    __shared__ float lds[TT][LDS_STRIDE];
    const int tid = threadIdx.x;
    const int k = tid >> 4;          // target within tile (gather phase)
    const int l = tid & 15;          // lane within target -> channel group
    const int t0 = blockIdx.x * TT;
    const int t = t0 + k;
    const int ty = t / WSd, tx = t % WSd;

    const float4* rt4 = (const float4*)ref_t;
    float4 acc[M4];
#pragma unroll
    for (int m = 0; m < M4; ++m) acc[m] = make_float4(0.f, 0.f, 0.f, 0.f);
    int n1 = 0;

    // dir1 (src->ref): pure 9-tap gather, inverted from the reference scatter
#pragma unroll
    for (int dy = -1; dy <= 1; ++dy) {
#pragma unroll
        for (int dx = -1; dx <= 1; ++dx) {
            const int sy = ty - dy, sx = tx - dx;
            if (sy >= 0 && sy < HSd && sx >= 0 && sx < WSd) {
                const int s = sy * WSd + sx;
                const int gy = nnf_sr[2 * s] + dy;
                const int gx = nnf_sr[2 * s + 1] + dx;
                if (gy >= 0 && gy < HRd && gx >= 0 && gx < WRd) {
                    const size_t base = (size_t)(gy * WRd + gx) * (Cd / 4);
#pragma unroll
                    for (int m = 0; m < M4; ++m) {
                        const float4 v = rt4[base + l + LPT * m];
                        acc[m].x = fmaf(v.x, W_SRC, acc[m].x);
                        acc[m].y = fmaf(v.y, W_SRC, acc[m].y);
                        acc[m].z = fmaf(v.z, W_SRC, acc[m].z);
                        acc[m].w = fmaf(v.w, W_SRC, acc[m].w);
                    }
                    ++n1;
                }
            }
        }
    }

    // dir2 (ref->src): precomputed per-target index list
    const int n2 = min(cnt[t], CAP);
    for (int j = 0; j < n2; ++j) {
        const size_t base = (size_t)list[t * CAP + j] * (Cd / 4);
#pragma unroll
        for (int m = 0; m < M4; ++m) {
            const float4 v = rt4[base + l + LPT * m];
            acc[m].x = fmaf(v.x, W_REF, acc[m].x);
            acc[m].y = fmaf(v.y, W_REF, acc[m].y);
            acc[m].z = fmaf(v.z, W_REF, acc[m].z);
            acc[m].w = fmaf(v.w, W_REF, acc[m].w);
        }
    }

    const float wsum = (float)n1 * W_SRC + (float)n2 * W_REF;
    const float inv = (wsum == 0.f) ? 0.f : 1.f / wsum;  // weight==0 -> guide 0 (ref divides by 1)

    // stage normalized guide into LDS (pixel-major), 16B-aligned rows
#pragma unroll
    for (int m = 0; m < M4; ++m) {
        float4 g;
        g.x = acc[m].x * inv;
        g.y = acc[m].y * inv;
        g.z = acc[m].z * inv;
        g.w = acc[m].w * inv;
        *reinterpret_cast<float4*>(&lds[k][4 * (l + LPT * m)]) = g;
    }
    __syncthreads();

    // transpose-read + blend + channel-major coalesced write (64B segments)
    const float mn = __uint_as_float(minmax[0]);
    const float mx = __uint_as_float(minmax[1]);
    const float inv_range = 1.f / (mx - mn);
    const int tt = tid & 15;   // target within tile (write phase)
    const int c0 = tid >> 4;   // 0..15
    const float rn = (resp[t0 + tt] - mn) * inv_range;
    const float w = (rn > TAUc) ? ALPHAc : 0.f;
    const float omw = 1.f - w;
#pragma unroll
    for (int m = 0; m < 32; ++m) {
        const int c = c0 + 16 * m;
        const float g = lds[tt][c];
        const size_t idx = (size_t)c * NS + t0 + tt;
        out[idx] = f_a[idx] * w + g * omw;
    }
}

// ---------------------------------------------------------------------------
extern "C" void kernel_launch(void* const* d_in, const int* in_sizes, int n_in,
                              void* d_out, int out_size, void* d_ws, size_t ws_size,
                              hipStream_t stream) {
    const float* ref    = (const float*)d_in[0];
    const float* f_a    = (const float*)d_in[1];
    const int*   nnf_sr = (const int*)d_in[2];
    const int*   nnf_rs = (const int*)d_in[3];
    float* out = (float*)d_out;

    char* ws = (char*)d_ws;
    size_t off = 0;
    float* ref_t = (float*)(ws + off);       off += (size_t)NR * Cd * sizeof(float);
    int*   list  = (int*)(ws + off);         off += (size_t)NS * CAP * sizeof(int);
    int*   cnt   = (int*)(ws + off);         off += (size_t)NS * sizeof(int);
    float* resp  = (float*)(ws + off);       off += (size_t)NS * sizeof(float);
    unsigned int* minmax = (unsigned int*)(ws + off); off += 16;

    hipMemsetAsync(cnt, 0, (size_t)NS * sizeof(int), stream);
    init_minmax<<<1, 1, 0, stream>>>(minmax);
    transpose_ref<<<dim3(NR / 32, Cd / 32), dim3(32, 8), 0, stream>>>(ref, ref_t);
    build_list<<<(NR + 255) / 256, 256, 0, stream>>>(nnf_rs, cnt, list);
    response_kernel<<<NS / 4 / 256, 256, 0, stream>>>(f_a, resp, minmax);
    gather_fused<<<NS / TT, 256, 0, stream>>>(ref_t, nnf_sr, cnt, list,
                                              f_a, resp, minmax, out);
}

// Round 7
// 432.280 us; speedup vs baseline: 1.0775x; 1.0521x over previous
//
#include <hip/hip_runtime.h>

// Problem constants (match reference)
constexpr int HSd = 192, WSd = 192, HRd = 192, WRd = 192;
constexpr int Cd  = 512;
constexpr int NS  = HSd * WSd;   // 36864 src pixels
constexpr int NR  = HRd * WRd;   // 36864 ref pixels
constexpr int CAP = 64;          // per-target dir2 list capacity (Poisson λ≈8.7)
constexpr float W_SRC = 1.0f / (float)NS;   // ws
constexpr float W_REF = 2.0f / (float)NR;   // wr
constexpr float TAUc   = 0.05f;
constexpr float ALPHAc = 0.8f;

constexpr int TT  = 16;            // targets per block (gather)
constexpr int LPT = 16;            // lanes per target
constexpr int M4  = Cd / 4 / LPT;  // 8 float4 accumulators per lane
constexpr int LDS_STRIDE = 516;    // words; 2-way conflicts only (free), 16B-aligned rows

// prep kernel block-role split
constexpr int TRB = (NR / 64) * (Cd / 64);  // 576*8 = 4608 transpose blocks
constexpr int RSB = 144;                    // response blocks (256 px each)
constexpr int BLB = 144;                    // build_list blocks (256 ref px each)

// ---------------------------------------------------------------------------
// Fused prep: blocks [0,TRB) transpose ref -> ref_t; [TRB,TRB+RSB) response +
// min/max; [TRB+RSB, ..) build dir2 lists. Roles are block-uniform (no lane
// divergence) and run concurrently, filling the machine.
__global__ __launch_bounds__(256)
void prep_kernel(const float* __restrict__ ref, const float* __restrict__ f_a,
                 const int* __restrict__ nnf_rs,
                 float* __restrict__ ref_t, int* __restrict__ cnt,
                 int* __restrict__ list, float* __restrict__ resp,
                 unsigned int* __restrict__ minmax) {
    __shared__ __align__(16) float smem[64 * 65];   // 16.6 KB (transpose tile / resp partials)
    const int b = blockIdx.x;
    const int t = threadIdx.x;

    if (b < TRB) {
        // ---- transpose role: 64px x 64ch tile, float4 both global sides ----
        const int pt = b % (NR / 64), ct = b / (NR / 64);
        const int p0 = pt * 64, c0 = ct * 64;
        const int fc = t & 15;        // float4 column
        const int r4 = t >> 4;        // 0..15
        const float4* rf4 = (const float4*)ref;
#pragma unroll
        for (int k = 0; k < 4; ++k) {
            const int row = r4 + 16 * k;                       // channel within tile
            const float4 v = rf4[((size_t)(c0 + row) * NR + p0) / 4 + fc];
            smem[row * 65 + 4 * fc + 0] = v.x;
            smem[row * 65 + 4 * fc + 1] = v.y;
            smem[row * 65 + 4 * fc + 2] = v.z;
            smem[row * 65 + 4 * fc + 3] = v.w;
        }
        __syncthreads();
        float4* rt4 = (float4*)ref_t;
#pragma unroll
        for (int k = 0; k < 4; ++k) {
            const int p = r4 + 16 * k;                         // pixel within tile
            float4 w;
            w.x = smem[(4 * fc + 0) * 65 + p];
            w.y = smem[(4 * fc + 1) * 65 + p];
            w.z = smem[(4 * fc + 2) * 65 + p];
            w.w = smem[(4 * fc + 3) * 65 + p];
            rt4[((size_t)(p0 + p) * Cd + c0) / 4 + fc] = w;
        }
    } else if (b < TRB + RSB) {
        // ---- response role: 256 px/block, 4 waves split channels, block-
        //      level min/max reduce -> 2 atomics per block (288 total) ----
        const int rb = b - TRB;
        const int lane = t & 63;      // float4 pixel within block
        const int q = t >> 6;         // channel quarter
        const int base4 = rb * 64;
        const float4* f4 = (const float4*)f_a;
        float4 a = make_float4(0.f, 0.f, 0.f, 0.f);
        for (int cc = 0; cc < Cd / 4; ++cc) {
            const int c = q * (Cd / 4) + cc;
            const float4 v = f4[(size_t)c * (NS / 4) + base4 + lane];
            a.x = fmaf(v.x, v.x, a.x);
            a.y = fmaf(v.y, v.y, a.y);
            a.z = fmaf(v.z, v.z, a.z);
            a.w = fmaf(v.w, v.w, a.w);
        }
        float4* part = (float4*)smem;
        part[q * 64 + lane] = a;
        __syncthreads();
        if (q == 0) {                 // one full wave (t 0..63)
            const float4 s0 = part[lane], s1 = part[64 + lane];
            const float4 s2 = part[128 + lane], s3 = part[192 + lane];
            float4 tot;
            tot.x = s0.x + s1.x + s2.x + s3.x;
            tot.y = s0.y + s1.y + s2.y + s3.y;
            tot.z = s0.z + s1.z + s2.z + s3.z;
            tot.w = s0.w + s1.w + s2.w + s3.w;
            ((float4*)resp)[base4 + lane] = tot;
            float mn = fminf(fminf(tot.x, tot.y), fminf(tot.z, tot.w));
            float mx = fmaxf(fmaxf(tot.x, tot.y), fmaxf(tot.z, tot.w));
#pragma unroll
            for (int off = 32; off; off >>= 1) {
                mn = fminf(mn, __shfl_xor(mn, off, 64));
                mx = fmaxf(mx, __shfl_xor(mx, off, 64));
            }
            if (lane == 0) {
                atomicMin(&minmax[0], __float_as_uint(mn));
                atomicMax(&minmax[1], __float_as_uint(mx));
            }
        }
    } else {
        // ---- build_list role: dir2 (ref->src) index-only scatter ----
        const int r = (b - TRB - RSB) * 256 + t;
        const int ry = r / WRd, rx = r % WRd;
        const int ty0 = nnf_rs[2 * r], tx0 = nnf_rs[2 * r + 1];
#pragma unroll
        for (int dy = -1; dy <= 1; ++dy) {
#pragma unroll
            for (int dx = -1; dx <= 1; ++dx) {
                const int ty = ty0 + dy, tx = tx0 + dx;
                const int gy = ry + dy,  gx = rx + dx;
                if (ty >= 0 && ty < HSd && tx >= 0 && tx < WSd &&
                    gy >= 0 && gy < HRd && gx >= 0 && gx < WRd) {
                    const int tt = ty * WSd + tx;
                    const int pos = atomicAdd(&cnt[tt], 1);
                    if (pos < CAP) list[tt * CAP + pos] = gy * WRd + gx;
                }
            }
        }
    }
}

// ---------------------------------------------------------------------------
// Fused vote-gather + normalize + LDS transpose + blend + channel-major write.
// (unchanged from Round 5 — matched its prediction; random-gather path is
//  fabric-BW-bound at ~3.8 TB/s regardless of occupancy)
__global__ __launch_bounds__(256)
void gather_fused(const float* __restrict__ ref_t, const int* __restrict__ nnf_sr,
                  const int* __restrict__ cnt, const int* __restrict__ list,
                  const float* __restrict__ f_a, const float* __restrict__ resp,
                  const unsigned int* __restrict__ minmax,
                  float* __restrict__ out) {
    __shared__ float lds[TT][LDS_STRIDE];
    const int tid = threadIdx.x;
    const int k = tid >> 4;          // target within tile (gather phase)
    const int l = tid & 15;          // lane within target -> channel group
    const int t0 = blockIdx.x * TT;
    const int t = t0 + k;
    const int ty = t / WSd, tx = t % WSd;

    const float4* rt4 = (const float4*)ref_t;
    float4 acc[M4];
#pragma unroll
    for (int m = 0; m < M4; ++m) acc[m] = make_float4(0.f, 0.f, 0.f, 0.f);
    int n1 = 0;

    // dir1 (src->ref): pure 9-tap gather, inverted from the reference scatter
#pragma unroll
    for (int dy = -1; dy <= 1; ++dy) {
#pragma unroll
        for (int dx = -1; dx <= 1; ++dx) {
            const int sy = ty - dy, sx = tx - dx;
            if (sy >= 0 && sy < HSd && sx >= 0 && sx < WSd) {
                const int s = sy * WSd + sx;
                const int gy = nnf_sr[2 * s] + dy;
                const int gx = nnf_sr[2 * s + 1] + dx;
                if (gy >= 0 && gy < HRd && gx >= 0 && gx < WRd) {
                    const size_t base = (size_t)(gy * WRd + gx) * (Cd / 4);
#pragma unroll
                    for (int m = 0; m < M4; ++m) {
                        const float4 v = rt4[base + l + LPT * m];
                        acc[m].x = fmaf(v.x, W_SRC, acc[m].x);
                        acc[m].y = fmaf(v.y, W_SRC, acc[m].y);
                        acc[m].z = fmaf(v.z, W_SRC, acc[m].z);
                        acc[m].w = fmaf(v.w, W_SRC, acc[m].w);
                    }
                    ++n1;
                }
            }
        }
    }

    // dir2 (ref->src): precomputed per-target index list
    const int n2 = min(cnt[t], CAP);
    for (int j = 0; j < n2; ++j) {
        const size_t base = (size_t)list[t * CAP + j] * (Cd / 4);
#pragma unroll
        for (int m = 0; m < M4; ++m) {
            const float4 v = rt4[base + l + LPT * m];
            acc[m].x = fmaf(v.x, W_REF, acc[m].x);
            acc[m].y = fmaf(v.y, W_REF, acc[m].y);
            acc[m].z = fmaf(v.z, W_REF, acc[m].z);
            acc[m].w = fmaf(v.w, W_REF, acc[m].w);
        }
    }

    const float wsum = (float)n1 * W_SRC + (float)n2 * W_REF;
    const float inv = (wsum == 0.f) ? 0.f : 1.f / wsum;  // weight==0 -> guide 0 (ref divides by 1)

    // stage normalized guide into LDS (pixel-major), 16B-aligned rows
#pragma unroll
    for (int m = 0; m < M4; ++m) {
        float4 g;
        g.x = acc[m].x * inv;
        g.y = acc[m].y * inv;
        g.z = acc[m].z * inv;
        g.w = acc[m].w * inv;
        *reinterpret_cast<float4*>(&lds[k][4 * (l + LPT * m)]) = g;
    }
    __syncthreads();

    // transpose-read + blend + channel-major coalesced write (64B segments)
    const float mn = __uint_as_float(minmax[0]);
    const float mx = __uint_as_float(minmax[1]);
    const float inv_range = 1.f / (mx - mn);
    const int tt = tid & 15;   // target within tile (write phase)
    const int c0 = tid >> 4;   // 0..15
    const float rn = (resp[t0 + tt] - mn) * inv_range;
    const float w = (rn > TAUc) ? ALPHAc : 0.f;
    const float omw = 1.f - w;
#pragma unroll
    for (int m = 0; m < 32; ++m) {
        const int c = c0 + 16 * m;
        const float g = lds[tt][c];
        const size_t idx = (size_t)c * NS + t0 + tt;
        out[idx] = f_a[idx] * w + g * omw;
    }
}

// ---------------------------------------------------------------------------
extern "C" void kernel_launch(void* const* d_in, const int* in_sizes, int n_in,
                              void* d_out, int out_size, void* d_ws, size_t ws_size,
                              hipStream_t stream) {
    const float* ref    = (const float*)d_in[0];
    const float* f_a    = (const float*)d_in[1];
    const int*   nnf_sr = (const int*)d_in[2];
    const int*   nnf_rs = (const int*)d_in[3];
    float* out = (float*)d_out;

    char* ws = (char*)d_ws;
    size_t off = 0;
    float* ref_t = (float*)(ws + off);       off += (size_t)NR * Cd * sizeof(float);
    int*   list  = (int*)(ws + off);         off += (size_t)NS * CAP * sizeof(int);
    int*   cnt   = (int*)(ws + off);         off += (size_t)NS * sizeof(int);
    float* resp  = (float*)(ws + off);       off += (size_t)NS * sizeof(float);
    unsigned int* minmax = (unsigned int*)(ws + off); off += 16;

    // cnt = 0; minmax[0](min) = 0xFFFFFFFF (uint-encoded upper bound, valid
    // since response >= 0); minmax[1](max) = 0
    hipMemsetAsync(cnt, 0, (size_t)NS * sizeof(int), stream);
    hipMemsetAsync(minmax, 0xFF, 4, stream);
    hipMemsetAsync(minmax + 1, 0, 4, stream);

    prep_kernel<<<TRB + RSB + BLB, 256, 0, stream>>>(ref, f_a, nnf_rs,
                                                     ref_t, cnt, list, resp, minmax);
    gather_fused<<<NS / TT, 256, 0, stream>>>(ref_t, nnf_sr, cnt, list,
                                              f_a, resp, minmax, out);
}